// Round 2
// baseline (1019.811 us; speedup 1.0000x reference)
//
#include <hip/hip_runtime.h>
#include <stdint.h>

#define B_   8
#define T_   2048
#define D_   1024
#define DFF_ 4096
#define M_   (B_ * T_)   // 16384

typedef __bf16 bf16;
typedef bf16  bf16x8 __attribute__((ext_vector_type(8)));
typedef bf16  bf16x4 __attribute__((ext_vector_type(4)));
typedef float f32x4  __attribute__((ext_vector_type(4)));

#define CAST_LDS(p) ((__attribute__((address_space(3))) void*)(p))
#define CAST_GLB(p) ((const __attribute__((address_space(1))) void*)(p))

// ---------------------------------------------------------------------------
// Weight converts.
// cvt_cat: fp32 -> bf16 with 128-row interleave: dst row nt*256+r  =
//   (r<128 ? W1[nt*128+r] : W2[nt*128+r-128]).
// ---------------------------------------------------------------------------
struct CatArgs {
    const float* w1[3];
    const float* w2[3];
    bf16* dst[3];
    int end[3];   // cumulative block ends: {2048, 4096, 12288}
};

__global__ __launch_bounds__(256) void cvt_cat_kernel(CatArgs a) {
    const int b = blockIdx.x;
    const int seg = (b >= a.end[0] ? 1 : 0) + (b >= a.end[1] ? 1 : 0);
    const int d = b - (seg ? a.end[seg - 1] : 0);
    const int nt = d >> 8;
    const int r = d & 255;
    const float* src = ((r < 128) ? a.w1[seg] : a.w2[seg]) +
                       (size_t)((nt << 7) + (r & 127)) * D_;
    bf16* dst = a.dst[seg] + (size_t)d * D_;
    const int t = threadIdx.x;
    const float4 v = ((const float4*)src)[t];
    bf16x4 o;
    o[0] = (bf16)v.x; o[1] = (bf16)v.y; o[2] = (bf16)v.z; o[3] = (bf16)v.w;
    ((bf16x4*)dst)[t] = o;
}

__global__ __launch_bounds__(256) void cvt_plain_kernel(const float* __restrict__ s,
                                                        bf16* __restrict__ d) {
    const int i = (blockIdx.x * 256 + threadIdx.x) * 4;
    const float4 v = *(const float4*)(s + i);
    bf16x4 o;
    o[0] = (bf16)v.x; o[1] = (bf16)v.y; o[2] = (bf16)v.z; o[3] = (bf16)v.w;
    *(bf16x4*)(d + i) = o;
}

// ---------------------------------------------------------------------------
// RMSNorm fp32-in (one block per row, D=1024, 256 threads x float4) -> bf16
// ---------------------------------------------------------------------------
__global__ __launch_bounds__(256) void rmsnorm_kernel(const float* __restrict__ x,
                                                      const float* __restrict__ w,
                                                      bf16* __restrict__ y) {
    const size_t row = blockIdx.x;
    const int t = threadIdx.x;
    const float4 v = ((const float4*)(x + row * D_))[t];
    float ss = v.x * v.x + v.y * v.y + v.z * v.z + v.w * v.w;
#pragma unroll
    for (int off = 32; off; off >>= 1) ss += __shfl_down(ss, off);
    __shared__ float red[4];
    if ((t & 63) == 0) red[t >> 6] = ss;
    __syncthreads();
    const float total = red[0] + red[1] + red[2] + red[3];
    const float rstd = rsqrtf(total * (1.0f / (float)D_) + 1e-6f);
    const float4 wv = ((const float4*)w)[t];
    bf16x4 o;
    o[0] = (bf16)(v.x * rstd * wv.x);
    o[1] = (bf16)(v.y * rstd * wv.y);
    o[2] = (bf16)(v.z * rstd * wv.z);
    o[3] = (bf16)(v.w * rstd * wv.w);
    ((bf16x4*)(y + row * D_))[t] = o;
}

// ---------------------------------------------------------------------------
// RMSNorm bf16-in (x1 path) -> bf16 out
// ---------------------------------------------------------------------------
__global__ __launch_bounds__(256) void rmsnorm_bf_kernel(const bf16* __restrict__ x,
                                                         const float* __restrict__ w,
                                                         bf16* __restrict__ y) {
    const size_t row = blockIdx.x;
    const int t = threadIdx.x;
    const bf16x4 xv = ((const bf16x4*)(x + row * D_))[t];
    float f0 = (float)xv[0], f1 = (float)xv[1], f2 = (float)xv[2], f3 = (float)xv[3];
    float ss = f0 * f0 + f1 * f1 + f2 * f2 + f3 * f3;
#pragma unroll
    for (int off = 32; off; off >>= 1) ss += __shfl_down(ss, off);
    __shared__ float red[4];
    if ((t & 63) == 0) red[t >> 6] = ss;
    __syncthreads();
    const float total = red[0] + red[1] + red[2] + red[3];
    const float rstd = rsqrtf(total * (1.0f / (float)D_) + 1e-6f);
    const float4 wv = ((const float4*)w)[t];
    bf16x4 o;
    o[0] = (bf16)(f0 * rstd * wv.x);
    o[1] = (bf16)(f1 * rstd * wv.y);
    o[2] = (bf16)(f2 * rstd * wv.z);
    o[3] = (bf16)(f3 * rstd * wv.w);
    ((bf16x4*)(y + row * D_))[t] = o;
}

// ---------------------------------------------------------------------------
// Chunked fused liquid-tanh + PLIF scan (warm-up contraction).
// ---------------------------------------------------------------------------
#define SCAN_C  32
#define SCAN_L  (T_ / SCAN_C)   // 64
#define SCAN_W  32
#define SCAN_PF 8

template <int N, int W0>
__device__ __forceinline__ void scan_body(const uint32_t* __restrict__ p,
                                          bf16* __restrict__ o, const int ts,
                                          const float pdec, const float om,
                                          const float th) {
    uint32_t buf[SCAN_PF];
#pragma unroll
    for (int i = 0; i < SCAN_PF; ++i) buf[i] = p[(size_t)i * D_];
    float h = 0.0f, v = 0.0f;
#pragma unroll 8
    for (int k = 0; k < N; ++k) {
        const uint32_t w = buf[k & (SCAN_PF - 1)];
        if (k + SCAN_PF < N) buf[k & (SCAN_PF - 1)] = p[(size_t)(k + SCAN_PF) * D_];
        const float a  = __builtin_bit_cast(float, w << 16);
        const float bb = __builtin_bit_cast(float, w & 0xffff0000u);
        const float xv = fmaf(a, h, bb);
        const float e2 = __expf(2.0f * xv);
        h = 1.0f - __fdividef(2.0f, 1.0f + e2);          // tanh(xv)
        const float vpre = fmaf(pdec, v, om * h);
        const float s = (vpre > th) ? 1.0f : 0.0f;
        v = vpre - s * th;
        if (k >= W0) o[(size_t)(ts + k) * D_] = (bf16)(s + h);
    }
}

__global__ __launch_bounds__(256) void scan_kernel(const uint32_t* __restrict__ ABp,
                                                   const float* __restrict__ log_tau,
                                                   const float* __restrict__ thr,
                                                   bf16* __restrict__ sp) {
    const int g = blockIdx.x * 256 + threadIdx.x;
    const int d = g & (D_ - 1);
    const int bc = g >> 10;
    const int b = bc / SCAN_C;
    const int c = bc % SCAN_C;
    const float pdec = __expf(-__expf(-log_tau[d]));
    const float om = 1.0f - pdec;
    const float th = thr[d];
    const int t0 = c * SCAN_L;
    const uint32_t* base = ABp + (size_t)b * (T_ * D_) + d;
    bf16* o = sp + (size_t)b * (T_ * D_) + d;
    if (c == 0) {
        scan_body<SCAN_L, 0>(base, o, 0, pdec, om, th);
    } else {
        const int ts = t0 - SCAN_W;
        scan_body<SCAN_L + SCAN_W, SCAN_W>(base + (size_t)ts * D_, o, ts, pdec, om, th);
    }
}

// ---------------------------------------------------------------------------
// 8-phase 256x256 GEMM (m201 schedule).  See round-0 comments for the stage
// schedule and swizzle derivation (unchanged, verified).
//
// NEW (round 1): XCD-locality block mapping.  Each XCD (bid&7) owns a
// contiguous 8-mt slab (A slab = 4 MB, ~L2-resident; A fetched ~once/XCD).
// Within-XCD dispatch order (c = bid>>3) tiles the slab so the ~32
// concurrently-resident blocks (1 block/CU, 32 CU/XCD) form an 8mt x 4nt
// square: unique operand slices per XCD per K-step drop (1+32) -> (8+4)
// -> predicted ~2.7x FETCH_SIZE reduction vs round 0's 1mt x 32nt line.
//   mt = (bid&7)*8 + (c&7),  nt = (c>>5)*4 + ((c>>3)&3)
// Bijective for NTM=64, NTN in {4,8,32} (grid % 8 == 0 in all call sites).
// ---------------------------------------------------------------------------

#define STG_A(tt, kh)                                                                  \
  { bf16* l_ = lA0 + ((((tt) & 1) << 1) + (kh)) * 8192;                                \
    const bf16* g_ = gA + (tt) * 64 + ((kh) << 5);                                     \
    __builtin_amdgcn_global_load_lds(CAST_GLB(g_), CAST_LDS(l_), 16, 0, 0);            \
    __builtin_amdgcn_global_load_lds(CAST_GLB(g_ + g2), CAST_LDS(l_ + 4096), 16, 0, 0); }
#define STG_B(tt, kh)                                                                  \
  { bf16* l_ = lB0 + ((((tt) & 1) << 1) + (kh)) * 8192;                                \
    const bf16* g_ = gB + (tt) * 64 + ((kh) << 5);                                     \
    __builtin_amdgcn_global_load_lds(CAST_GLB(g_), CAST_LDS(l_), 16, 0, 0);            \
    __builtin_amdgcn_global_load_lds(CAST_GLB(g_ + g2), CAST_LDS(l_ + 4096), 16, 0, 0); }
// swizzle XOR depends only on lane15 (all row-base terms are multiples of 8),
// hoisted to per-lane constant `swz` (elements).
#define DSREAD_A(KS, MH)                                                               \
  { const bf16* As_ = smA + (cb + (KS)) * 8192 + swz;                                  \
    _Pragma("unroll")                                                                  \
    for (int i = 0; i < 4; ++i)                                                        \
      af[i] = *(const bf16x8*)(As_ + (mr128 + (MH) * 64 + i * 16 + lane15) * 32);      \
  }
#define DSREAD_B(KS)                                                                   \
  { const bf16* Bs_ = smB + (cb + (KS)) * 8192 + swz;                                  \
    _Pragma("unroll")                                                                  \
    for (int j = 0; j < 4; ++j)                                                        \
      bfr[j] = *(const bf16x8*)(Bs_ + (nc64 + j * 16 + lane15) * 32);                  \
  }
#define MFMA16(MH)                                                                     \
  __builtin_amdgcn_s_setprio(1);                                                       \
  _Pragma("unroll")                                                                    \
  for (int i = 0; i < 4; ++i)                                                          \
    _Pragma("unroll")                                                                  \
    for (int j = 0; j < 4; ++j)                                                        \
      acc[(MH) * 4 + i][j] = __builtin_amdgcn_mfma_f32_16x16x32_bf16(                  \
          af[i], bfr[j], acc[(MH) * 4 + i][j], 0, 0, 0);                               \
  __builtin_amdgcn_s_setprio(0);
#define GBAR() __builtin_amdgcn_s_barrier()
#define LGKM0() asm volatile("s_waitcnt lgkmcnt(0)" ::: "memory")

template <int MODE>
__global__ __launch_bounds__(512, 2) void gemm8_kernel(
    const bf16* __restrict__ A, const bf16* __restrict__ Bw,
    const int Ncat, const int K, const int Nlog,
    const float* __restrict__ b1, const float* __restrict__ b2,
    const float* __restrict__ extra, const bf16* __restrict__ extra_bf,
    void* __restrict__ outp) {
    constexpr bool DUAL = (MODE != 3);
    __shared__ bf16 smem[65536] __attribute__((aligned(16)));   // 128 KiB
    bf16* const smA = smem;             // 4 slots x 8192 elems ([256][32] each)
    bf16* const smB = smem + 32768;

    const int tid = threadIdx.x;
    const int wave = tid >> 6;
    const int lane = tid & 63;
    const int lane15 = lane & 15;
    const int quad = lane >> 4;
    const int mr = wave >> 2;          // 0..1
    const int nc = wave & 3;           // 0..3
    const int mr128 = mr * 128;
    const int nc64 = nc * 64;
    const int swz = (quad ^ ((lane15 >> 1) & 3)) << 3;   // constant per lane

    // XCD-locality mapping: 8-mt slab per XCD, 8mt x 4nt concurrency tile.
    const int xcd = blockIdx.x & 7;
    const int c = blockIdx.x >> 3;
    const int mt = xcd * 8 + (c & 7);
    const int nt = (c >> 5) * 4 + ((c >> 3) & 3);

    // staging addressing: chunk = q*512 + tid, row = chunk>>2, dest linear,
    // source column XOR-swizzled to match the ds_read-side swizzle.
    const int srow = tid >> 2;                               // 0..127 (q=0)
    const int scol = (((tid & 3) ^ ((srow >> 1) & 3)) << 3); // 0/8/16/24 elems
    const bf16* const gA = A + (size_t)(mt * 256 + srow) * K + scol;
    const bf16* const gB = Bw + (size_t)(nt * 256 + srow) * K + scol;
    const size_t g2 = (size_t)128 * K;                       // q=1: rows +128
    bf16* const lA0 = smA + (wave << 9);
    bf16* const lB0 = smB + (wave << 9);

    const int NT = K >> 6;

    f32x4 acc[8][4] = {};
    bf16x8 af[4];
    bf16x8 bfr[4];

    // prologue: tile 0 fully + 3 half-tiles of tile 1 (order = steady pattern)
    STG_B(0, 0); STG_A(0, 0); STG_B(0, 1); STG_A(0, 1);
    asm volatile("s_waitcnt vmcnt(4)" ::: "memory");
    STG_B(1, 0); STG_A(1, 0); STG_B(1, 1);
    asm volatile("s_waitcnt vmcnt(6)" ::: "memory");
    GBAR();

    for (int t = 0; t < NT; ++t) {
        const int cb = (t & 1) << 1;   // compute-buffer slot base

        // phase 1: (mh0, k0)
        DSREAD_A(0, 0); DSREAD_B(0);
        if (t + 1 < NT) STG_A(t + 1, 1);
        GBAR(); LGKM0();
        MFMA16(0);
        GBAR();

        // phase 2: (mh1, k0) — B-frags held in regs
        DSREAD_A(0, 1);
        if (t + 2 < NT) STG_B(t + 2, 0);
        GBAR(); LGKM0();
        MFMA16(1);
        GBAR();

        // phase 3: (mh0, k1)
        DSREAD_A(1, 0); DSREAD_B(1);
        if (t + 2 < NT) STG_A(t + 2, 0);
        GBAR(); LGKM0();
        MFMA16(0);
        GBAR();

        // phase 4: (mh1, k1) + counted vmcnt (never 0 in steady state)
        DSREAD_A(1, 1);
        if (t + 2 < NT) {
            STG_B(t + 2, 1);
            asm volatile("s_waitcnt vmcnt(6)" ::: "memory");
        } else {
            asm volatile("s_waitcnt vmcnt(0)" ::: "memory");
        }
        GBAR(); LGKM0();
        MFMA16(1);
        GBAR();
    }

    // ---------------- epilogue ----------------
    if constexpr (DUAL) {
        // W2-side waves park acc in (now dead) staging LDS; W1-side fuses.
        float* const xch = (float*)smem;   // 4 slots x 8192 f32 = 128 KiB
        if (nc >= 2) {
            float* const dst = xch + (mr * 2 + (nc - 2)) * 8192;
#pragma unroll
            for (int i8 = 0; i8 < 8; ++i8)
#pragma unroll
                for (int j = 0; j < 4; ++j)
#pragma unroll
                    for (int r = 0; r < 4; ++r)
                        dst[(i8 * 16 + quad * 4 + r) * 64 + j * 16 + lane15] =
                            acc[i8][j][r];
        }
        __syncthreads();
        if (nc < 2) {
            const float* const src = xch + (mr * 2 + nc) * 8192;
            const int mbase = mt * 256 + mr128;
            const int nbase = nt * 128 + nc64;
#pragma unroll
            for (int i8 = 0; i8 < 8; ++i8)
#pragma unroll
                for (int j = 0; j < 4; ++j)
#pragma unroll
                    for (int r = 0; r < 4; ++r) {
                        const int rl = i8 * 16 + quad * 4 + r;
                        const int cl = j * 16 + lane15;
                        const int m = mbase + rl;
                        const int n = nbase + cl;
                        const size_t idx = (size_t)m * Nlog + n;
                        const float v1 = acc[i8][j][r];
                        const float v2 = src[rl * 64 + cl];
                        if constexpr (MODE == 0) {
                            const float dl = v1 + b1[n];
                            const float spv = (dl > 20.0f) ? dl : log1pf(__expf(dl));
                            const float bv = spv * (v2 + b2[n]);
                            const float av = __expf(-spv * __expf(extra[n]));
                            const uint32_t pa =
                                (uint32_t)__builtin_bit_cast(unsigned short, (bf16)av);
                            const uint32_t pb =
                                (uint32_t)__builtin_bit_cast(unsigned short, (bf16)bv);
                            ((uint32_t*)outp)[idx] = pa | (pb << 16);
                        } else if constexpr (MODE == 1) {
                            const float syn = v1 + b1[n];
                            const float z = v2 + b2[n];
                            const float gate = 1.0f / (1.0f + __expf(-z));
                            ((bf16*)outp)[idx] = (bf16)(extra[idx] + syn * gate);
                        } else {   // MODE 2
                            const float sg = v1 / (1.0f + __expf(-v1));
                            ((bf16*)outp)[idx] = (bf16)(sg * v2);
                        }
                    }
        }
    } else {   // MODE 3: single-B, direct write
        const int mbase = mt * 256 + mr128;
        const int nbase = nt * 256 + nc64;
#pragma unroll
        for (int i8 = 0; i8 < 8; ++i8)
#pragma unroll
            for (int j = 0; j < 4; ++j)
#pragma unroll
                for (int r = 0; r < 4; ++r) {
                    const int m = mbase + i8 * 16 + quad * 4 + r;
                    const int n = nbase + j * 16 + lane15;
                    const size_t idx = (size_t)m * Nlog + n;
                    ((float*)outp)[idx] = (float)extra_bf[idx] + acc[i8][j][r];
                }
    }
}

#undef STG_A
#undef STG_B
#undef DSREAD_A
#undef DSREAD_B
#undef MFMA16
#undef GBAR
#undef LGKM0

// ---------------------------------------------------------------------------
extern "C" void kernel_launch(void* const* d_in, const int* in_sizes, int n_in,
                              void* d_out, int out_size, void* d_ws, size_t ws_size,
                              hipStream_t stream) {
    const float* x        = (const float*)d_in[0];
    const float* rms_w1   = (const float*)d_in[1];
    const float* rms_w2   = (const float*)d_in[2];
    const float* delta_w  = (const float*)d_in[3];
    const float* delta_b  = (const float*)d_in[4];
    const float* b_w      = (const float*)d_in[5];
    const float* b_b      = (const float*)d_in[6];
    const float* A_log    = (const float*)d_in[7];
    const float* log_tau  = (const float*)d_in[8];
    const float* plif_thr = (const float*)d_in[9];
    const float* syn_w    = (const float*)d_in[10];
    const float* syn_b    = (const float*)d_in[11];
    const float* gate_w   = (const float*)d_in[12];
    const float* gate_b   = (const float*)d_in[13];
    const float* ffn_g_w  = (const float*)d_in[14];
    const float* ffn_u_w  = (const float*)d_in[15];
    const float* ffn_d_w  = (const float*)d_in[16];

    char* ws = (char*)d_ws;
    const size_t MB = 1024ull * 1024ull;
    // cat-interleaved bf16 weights: [0,32MB)
    bf16* wcat_db = (bf16*)(ws + 0 * MB);    // [2048,1024]  4MB
    bf16* wcat_sg = (bf16*)(ws + 4 * MB);    // [2048,1024]  4MB
    bf16* wcat_gu = (bf16*)(ws + 8 * MB);    // [8192,1024] 16MB
    bf16* wd      = (bf16*)(ws + 24 * MB);   // [1024,4096]  8MB
    // phase-1 buffers (all dead before act is written):
    bf16*     y1      = (bf16*)(ws + 32 * MB);       // 32MB
    uint32_t* ABp     = (uint32_t*)(ws + 64 * MB);   // 64MB
    bf16*     spikein = (bf16*)(ws + 128 * MB);      // 32MB
    // persistent:
    bf16* x1 = (bf16*)(ws + 160 * MB);               // 32MB
    bf16* y2 = (bf16*)(ws + 224 * MB);               // 32MB
    // act aliases the dead phase-1 region [32MB,160MB): 16384*4096*2 = 128MB
    bf16* act = (bf16*)(ws + 32 * MB);
    float* outF = (float*)d_out;

    // --- weight converts ---
    CatArgs ca;
    ca.w1[0] = delta_w; ca.w2[0] = b_w;     ca.dst[0] = wcat_db;
    ca.w1[1] = syn_w;   ca.w2[1] = gate_w;  ca.dst[1] = wcat_sg;
    ca.w1[2] = ffn_g_w; ca.w2[2] = ffn_u_w; ca.dst[2] = wcat_gu;
    ca.end[0] = 2048; ca.end[1] = 4096; ca.end[2] = 12288;
    cvt_cat_kernel<<<12288, 256, 0, stream>>>(ca);
    cvt_plain_kernel<<<(D_ * DFF_) / 1024, 256, 0, stream>>>(ffn_d_w, wd);

    // --- RMSNorm 1 ---
    rmsnorm_kernel<<<M_, 256, 0, stream>>>(x, rms_w1, y1);

    // --- dual GEMM (cat): delta/b -> packed (A_t, b_t) ---
    gemm8_kernel<0><<<(2048 / 256) * (M_ / 256), 512, 0, stream>>>(
        y1, wcat_db, 2048, D_, D_, delta_b, b_b, A_log, nullptr, ABp);

    // --- chunked fused liquid + PLIF scans ---
    scan_kernel<<<(B_ * SCAN_C * D_) / 256, 256, 0, stream>>>(ABp, log_tau, plif_thr, spikein);

    // --- dual GEMM (cat): syn/gate -> x1 = x + syn*sigmoid(gate) ---
    gemm8_kernel<1><<<(2048 / 256) * (M_ / 256), 512, 0, stream>>>(
        spikein, wcat_sg, 2048, D_, D_, syn_b, gate_b, x, nullptr, x1);

    // --- RMSNorm 2 (bf16 in) ---
    rmsnorm_bf_kernel<<<M_, 256, 0, stream>>>(x1, rms_w2, y2);

    // --- dual GEMM (cat): ffn gate/up -> act = silu(g)*u ---
    gemm8_kernel<2><<<(8192 / 256) * (M_ / 256), 512, 0, stream>>>(
        y2, wcat_gu, 8192, D_, DFF_, nullptr, nullptr, nullptr, nullptr, act);

    // --- GEMM: ffn down + residual -> out ---
    gemm8_kernel<3><<<(1024 / 256) * (M_ / 256), 512, 0, stream>>>(
        act, wd, 1024, DFF_, D_, nullptr, nullptr, nullptr, x1, outF);
}

// Round 3
// 886.427 us; speedup vs baseline: 1.1505x; 1.1505x over previous
//
#include <hip/hip_runtime.h>
#include <stdint.h>

#define B_   8
#define T_   2048
#define D_   1024
#define DFF_ 4096
#define M_   (B_ * T_)   // 16384

typedef __bf16 bf16;
typedef bf16  bf16x8 __attribute__((ext_vector_type(8)));
typedef bf16  bf16x4 __attribute__((ext_vector_type(4)));
typedef float f32x4  __attribute__((ext_vector_type(4)));

#define CAST_LDS(p) ((__attribute__((address_space(3))) void*)(p))
#define CAST_GLB(p) ((const __attribute__((address_space(1))) void*)(p))

// ---------------------------------------------------------------------------
// Fused fp32 -> bf16 convert for all 7 weight tensors (one launch).
// ---------------------------------------------------------------------------
struct CvtArgs {
    const float* s[7];
    bf16* d[7];
    int nblk[7];   // cumulative block offsets (exclusive end)
};

__global__ __launch_bounds__(256) void f2bf_all_kernel(CvtArgs a) {
    int blk = blockIdx.x;
    int seg = 0;
#pragma unroll
    for (int i = 0; i < 7; ++i) seg += (blk >= a.nblk[i]) ? 1 : 0;
    const int base = (seg == 0) ? 0 : a.nblk[seg - 1];
    const int i = ((blk - base) * 256 + threadIdx.x) * 4;
    const float4 v = *(const float4*)(a.s[seg] + i);
    bf16x4 o;
    o[0] = (bf16)v.x; o[1] = (bf16)v.y; o[2] = (bf16)v.z; o[3] = (bf16)v.w;
    *(bf16x4*)(a.d[seg] + i) = o;
}

// ---------------------------------------------------------------------------
// RMSNorm fp32-in (one block per row, D=1024, 256 threads x float4) -> bf16
// ---------------------------------------------------------------------------
__global__ __launch_bounds__(256) void rmsnorm_kernel(const float* __restrict__ x,
                                                      const float* __restrict__ w,
                                                      bf16* __restrict__ y) {
    const size_t row = blockIdx.x;
    const int t = threadIdx.x;
    const float4 v = ((const float4*)(x + row * D_))[t];
    float ss = v.x * v.x + v.y * v.y + v.z * v.z + v.w * v.w;
#pragma unroll
    for (int off = 32; off; off >>= 1) ss += __shfl_down(ss, off);
    __shared__ float red[4];
    if ((t & 63) == 0) red[t >> 6] = ss;
    __syncthreads();
    const float total = red[0] + red[1] + red[2] + red[3];
    const float rstd = rsqrtf(total * (1.0f / (float)D_) + 1e-6f);
    const float4 wv = ((const float4*)w)[t];
    bf16x4 o;
    o[0] = (bf16)(v.x * rstd * wv.x);
    o[1] = (bf16)(v.y * rstd * wv.y);
    o[2] = (bf16)(v.z * rstd * wv.z);
    o[3] = (bf16)(v.w * rstd * wv.w);
    ((bf16x4*)(y + row * D_))[t] = o;
}

// ---------------------------------------------------------------------------
// RMSNorm bf16-in (x1 path) -> bf16 out
// ---------------------------------------------------------------------------
__global__ __launch_bounds__(256) void rmsnorm_bf_kernel(const bf16* __restrict__ x,
                                                         const float* __restrict__ w,
                                                         bf16* __restrict__ y) {
    const size_t row = blockIdx.x;
    const int t = threadIdx.x;
    const bf16x4 xv = ((const bf16x4*)(x + row * D_))[t];
    float f0 = (float)xv[0], f1 = (float)xv[1], f2 = (float)xv[2], f3 = (float)xv[3];
    float ss = f0 * f0 + f1 * f1 + f2 * f2 + f3 * f3;
#pragma unroll
    for (int off = 32; off; off >>= 1) ss += __shfl_down(ss, off);
    __shared__ float red[4];
    if ((t & 63) == 0) red[t >> 6] = ss;
    __syncthreads();
    const float total = red[0] + red[1] + red[2] + red[3];
    const float rstd = rsqrtf(total * (1.0f / (float)D_) + 1e-6f);
    const float4 wv = ((const float4*)w)[t];
    bf16x4 o;
    o[0] = (bf16)(f0 * rstd * wv.x);
    o[1] = (bf16)(f1 * rstd * wv.y);
    o[2] = (bf16)(f2 * rstd * wv.z);
    o[3] = (bf16)(f3 * rstd * wv.w);
    ((bf16x4*)(y + row * D_))[t] = o;
}

// ---------------------------------------------------------------------------
// Chunked fused liquid-tanh + PLIF scan (warm-up contraction).
// ---------------------------------------------------------------------------
#define SCAN_C  32
#define SCAN_L  (T_ / SCAN_C)   // 64
#define SCAN_W  32
#define SCAN_PF 8

template <int N, int W0>
__device__ __forceinline__ void scan_body(const uint32_t* __restrict__ p,
                                          bf16* __restrict__ o, const int ts,
                                          const float pdec, const float om,
                                          const float th) {
    uint32_t buf[SCAN_PF];
#pragma unroll
    for (int i = 0; i < SCAN_PF; ++i) buf[i] = p[(size_t)i * D_];
    float h = 0.0f, v = 0.0f;
#pragma unroll 8
    for (int k = 0; k < N; ++k) {
        const uint32_t w = buf[k & (SCAN_PF - 1)];
        if (k + SCAN_PF < N) buf[k & (SCAN_PF - 1)] = p[(size_t)(k + SCAN_PF) * D_];
        const float a  = __builtin_bit_cast(float, w << 16);
        const float bb = __builtin_bit_cast(float, w & 0xffff0000u);
        const float xv = fmaf(a, h, bb);
        const float e2 = __expf(2.0f * xv);
        h = 1.0f - __fdividef(2.0f, 1.0f + e2);          // tanh(xv)
        const float vpre = fmaf(pdec, v, om * h);
        const float s = (vpre > th) ? 1.0f : 0.0f;
        v = vpre - s * th;
        if (k >= W0) o[(size_t)(ts + k) * D_] = (bf16)(s + h);
    }
}

__global__ __launch_bounds__(256) void scan_kernel(const uint32_t* __restrict__ ABp,
                                                   const float* __restrict__ log_tau,
                                                   const float* __restrict__ thr,
                                                   bf16* __restrict__ sp) {
    const int g = blockIdx.x * 256 + threadIdx.x;
    const int d = g & (D_ - 1);
    const int bc = g >> 10;
    const int b = bc / SCAN_C;
    const int c = bc % SCAN_C;
    const float pdec = __expf(-__expf(-log_tau[d]));
    const float om = 1.0f - pdec;
    const float th = thr[d];
    const int t0 = c * SCAN_L;
    const uint32_t* base = ABp + (size_t)b * (T_ * D_) + d;
    bf16* o = sp + (size_t)b * (T_ * D_) + d;
    if (c == 0) {
        scan_body<SCAN_L, 0>(base, o, 0, pdec, om, th);
    } else {
        const int ts = t0 - SCAN_W;
        scan_body<SCAN_L + SCAN_W, SCAN_W>(base + (size_t)ts * D_, o, ts, pdec, om, th);
    }
}

// ---------------------------------------------------------------------------
// (Dual-)GEMM 128x128 (round-0 verified structure, 853 TF at K=1024):
// C_i[M,N] = A[M,K] @ W_i[N,K]^T for i < NB, fused epilogue.
// 2 blocks/CU, BK=64 as two half-tiles per barrier pair.
// MODE 0: delta/b   -> pack bf16(A_t) | bf16(b_t)<<16 into u32 out
// MODE 1: syn/gate  -> out = x + syn*sigmoid(gate)   (bf16 out, fp32 x in)
// MODE 2: ffn g/u   -> out = silu(g)*u               (bf16)
// ---------------------------------------------------------------------------
template <int NB, int MODE>
__global__ __launch_bounds__(256, 2) void gemm_kernel(
    const bf16* __restrict__ A, const bf16* __restrict__ W1, const bf16* __restrict__ W2,
    const int M, const int N, const int K,
    const float* __restrict__ b1, const float* __restrict__ b2,
    const float* __restrict__ extra, const bf16* __restrict__ extra_bf,
    void* __restrict__ outp) {
    __shared__ bf16 As[2][128 * 32];
    __shared__ bf16 Bs[NB][2][128 * 32];

    const int tid = threadIdx.x;
    const int wave = tid >> 6;
    const int lane = tid & 63;
    const int lane15 = lane & 15;
    const int quad = lane >> 4;
    const int m0 = blockIdx.y * 128;
    const int n0 = blockIdx.x * 128;
    const int wm = (wave >> 1) * 64;
    const int wn = (wave & 1) * 64;

    f32x4 acc[NB][4][4] = {};

    const int srow = lane >> 2;          // 0..15
    const int scol = (lane & 3) * 8;     // 0,8,16,24
    const bf16* gA = A + (size_t)(m0 + wave * 32 + srow) * K + scol;
    const bf16* gW[2];
    gW[0] = W1 + (size_t)(n0 + wave * 32 + srow) * K + scol;
    if (NB > 1) gW[1] = W2 + (size_t)(n0 + wave * 32 + srow) * K + scol;

    const int lofs = (wave * 32) * 32;

    for (int k0 = 0; k0 < K; k0 += 64) {
#pragma unroll
        for (int h = 0; h < 2; ++h) {
            const int kh = k0 + h * 32;
            bf16* lA = &As[h][lofs];
            __builtin_amdgcn_global_load_lds(CAST_GLB(gA + kh),          CAST_LDS(lA),           16, 0, 0);
            __builtin_amdgcn_global_load_lds(CAST_GLB(gA + kh + 16 * K), CAST_LDS(lA + 16 * 32), 16, 0, 0);
#pragma unroll
            for (int nb = 0; nb < NB; ++nb) {
                bf16* lB = &Bs[nb][h][lofs];
                __builtin_amdgcn_global_load_lds(CAST_GLB(gW[nb] + kh),          CAST_LDS(lB),           16, 0, 0);
                __builtin_amdgcn_global_load_lds(CAST_GLB(gW[nb] + kh + 16 * K), CAST_LDS(lB + 16 * 32), 16, 0, 0);
            }
        }
        __syncthreads();   // one drain covers both half-tiles (12 loads/wave)

#pragma unroll
        for (int h = 0; h < 2; ++h) {
            bf16x8 af[4];
#pragma unroll
            for (int i = 0; i < 4; ++i)
                af[i] = *(const bf16x8*)(&As[h][(wm + i * 16 + lane15) * 32 + quad * 8]);
#pragma unroll
            for (int nb = 0; nb < NB; ++nb) {
#pragma unroll
                for (int j = 0; j < 4; ++j) {
                    const bf16x8 bfj = *(const bf16x8*)(&Bs[nb][h][(wn + j * 16 + lane15) * 32 + quad * 8]);
#pragma unroll
                    for (int i = 0; i < 4; ++i)
                        acc[nb][i][j] = __builtin_amdgcn_mfma_f32_16x16x32_bf16(af[i], bfj, acc[nb][i][j], 0, 0, 0);
                }
            }
        }
        __syncthreads();   // all waves done reading before next overwrite
    }

    // epilogue: D[row=quad*4+r][col=lane15] per 16x16 tile (verified layout)
#pragma unroll
    for (int i = 0; i < 4; ++i) {
#pragma unroll
        for (int r = 0; r < 4; ++r) {
            const int m = m0 + wm + i * 16 + quad * 4 + r;
#pragma unroll
            for (int j = 0; j < 4; ++j) {
                const int n = n0 + wn + j * 16 + lane15;
                const size_t idx = (size_t)m * N + n;
                const float v1 = acc[0][i][j][r];
                if constexpr (MODE == 0) {
                    const float v2 = acc[1][i][j][r];
                    const float dl = v1 + b1[n];
                    const float spv = (dl > 20.0f) ? dl : log1pf(__expf(dl));   // softplus
                    const float bv = spv * (v2 + b2[n]);
                    const float av = __expf(-spv * __expf(extra[n]));           // extra = A_log
                    const uint32_t pa = (uint32_t)__builtin_bit_cast(unsigned short, (bf16)av);
                    const uint32_t pb = (uint32_t)__builtin_bit_cast(unsigned short, (bf16)bv);
                    ((uint32_t*)outp)[idx] = pa | (pb << 16);
                } else if constexpr (MODE == 1) {
                    const float v2 = acc[1][i][j][r];
                    const float syn = v1 + b1[n];
                    const float z = v2 + b2[n];
                    const float gate = 1.0f / (1.0f + __expf(-z));
                    ((bf16*)outp)[idx] = (bf16)(extra[idx] + syn * gate);       // extra = x
                } else {   // MODE 2
                    const float v2 = acc[1][i][j][r];
                    const float sg = v1 / (1.0f + __expf(-v1));                 // silu
                    ((bf16*)outp)[idx] = (bf16)(sg * v2);
                }
            }
        }
    }
}

// ---------------------------------------------------------------------------
// 8-phase 256x256 GEMM (m201 schedule) — used ONLY for the down-GEMM
// (K=4096 -> NT=64 amortizes prologue/epilogue; grid=256 = 1 block/CU).
// Stage schedule + both-sides swizzle verified in rounds 1-2 (passed twice).
// XCD-locality map: 8-mt slab per XCD; concurrency tile 8mt x 4nt.
// MODE 3 only: out = x1 + acc (fp32).
// ---------------------------------------------------------------------------

#define STG_A(tt, kh)                                                                  \
  { bf16* l_ = lA0 + ((((tt) & 1) << 1) + (kh)) * 8192;                                \
    const bf16* g_ = gA + (tt) * 64 + ((kh) << 5);                                     \
    __builtin_amdgcn_global_load_lds(CAST_GLB(g_), CAST_LDS(l_), 16, 0, 0);            \
    __builtin_amdgcn_global_load_lds(CAST_GLB(g_ + g2), CAST_LDS(l_ + 4096), 16, 0, 0); }
#define STG_B(tt, kh)                                                                  \
  { bf16* l_ = lB0 + ((((tt) & 1) << 1) + (kh)) * 8192;                                \
    const bf16* g_ = gB + (tt) * 64 + ((kh) << 5);                                     \
    __builtin_amdgcn_global_load_lds(CAST_GLB(g_), CAST_LDS(l_), 16, 0, 0);            \
    __builtin_amdgcn_global_load_lds(CAST_GLB(g_ + g2), CAST_LDS(l_ + 4096), 16, 0, 0); }
#define DSREAD_A(KS, MH)                                                               \
  { const bf16* As_ = smA + (cb + (KS)) * 8192 + swz;                                  \
    _Pragma("unroll")                                                                  \
    for (int i = 0; i < 4; ++i)                                                        \
      af[i] = *(const bf16x8*)(As_ + (mr128 + (MH) * 64 + i * 16 + lane15) * 32);      \
  }
#define DSREAD_B(KS)                                                                   \
  { const bf16* Bs_ = smB + (cb + (KS)) * 8192 + swz;                                  \
    _Pragma("unroll")                                                                  \
    for (int j = 0; j < 4; ++j)                                                        \
      bfr[j] = *(const bf16x8*)(Bs_ + (nc64 + j * 16 + lane15) * 32);                  \
  }
#define MFMA16(MH)                                                                     \
  __builtin_amdgcn_s_setprio(1);                                                       \
  _Pragma("unroll")                                                                    \
  for (int i = 0; i < 4; ++i)                                                          \
    _Pragma("unroll")                                                                  \
    for (int j = 0; j < 4; ++j)                                                        \
      acc[(MH) * 4 + i][j] = __builtin_amdgcn_mfma_f32_16x16x32_bf16(                  \
          af[i], bfr[j], acc[(MH) * 4 + i][j], 0, 0, 0);                               \
  __builtin_amdgcn_s_setprio(0);
#define GBAR() __builtin_amdgcn_s_barrier()
#define LGKM0() asm volatile("s_waitcnt lgkmcnt(0)" ::: "memory")

template <int MODE>
__global__ __launch_bounds__(512, 2) void gemm8_kernel(
    const bf16* __restrict__ A, const bf16* __restrict__ Bw,
    const int Ncat, const int K, const int Nlog,
    const float* __restrict__ b1, const float* __restrict__ b2,
    const float* __restrict__ extra, const bf16* __restrict__ extra_bf,
    void* __restrict__ outp) {
    __shared__ bf16 smem[65536] __attribute__((aligned(16)));   // 128 KiB
    bf16* const smA = smem;             // 4 slots x 8192 elems ([256][32] each)
    bf16* const smB = smem + 32768;

    const int tid = threadIdx.x;
    const int wave = tid >> 6;
    const int lane = tid & 63;
    const int lane15 = lane & 15;
    const int quad = lane >> 4;
    const int mr = wave >> 2;          // 0..1
    const int nc = wave & 3;           // 0..3
    const int mr128 = mr * 128;
    const int nc64 = nc * 64;
    const int swz = (quad ^ ((lane15 >> 1) & 3)) << 3;   // constant per lane

    // XCD-locality mapping: 8-mt slab per XCD, 8mt x 4nt concurrency tile.
    const int xcd = blockIdx.x & 7;
    const int c = blockIdx.x >> 3;
    const int mt = xcd * 8 + (c & 7);
    const int nt = (c >> 5) * 4 + ((c >> 3) & 3);

    const int srow = tid >> 2;                               // 0..127 (q=0)
    const int scol = (((tid & 3) ^ ((srow >> 1) & 3)) << 3); // 0/8/16/24 elems
    const bf16* const gA = A + (size_t)(mt * 256 + srow) * K + scol;
    const bf16* const gB = Bw + (size_t)(nt * 256 + srow) * K + scol;
    const size_t g2 = (size_t)128 * K;                       // q=1: rows +128
    bf16* const lA0 = smA + (wave << 9);
    bf16* const lB0 = smB + (wave << 9);

    const int NT = K >> 6;

    f32x4 acc[8][4] = {};
    bf16x8 af[4];
    bf16x8 bfr[4];

    // prologue: tile 0 fully + 3 half-tiles of tile 1 (order = steady pattern)
    STG_B(0, 0); STG_A(0, 0); STG_B(0, 1); STG_A(0, 1);
    asm volatile("s_waitcnt vmcnt(4)" ::: "memory");
    STG_B(1, 0); STG_A(1, 0); STG_B(1, 1);
    asm volatile("s_waitcnt vmcnt(6)" ::: "memory");
    GBAR();

    for (int t = 0; t < NT; ++t) {
        const int cb = (t & 1) << 1;   // compute-buffer slot base

        // phase 1: (mh0, k0)
        DSREAD_A(0, 0); DSREAD_B(0);
        if (t + 1 < NT) STG_A(t + 1, 1);
        GBAR(); LGKM0();
        MFMA16(0);
        GBAR();

        // phase 2: (mh1, k0) — B-frags held in regs
        DSREAD_A(0, 1);
        if (t + 2 < NT) STG_B(t + 2, 0);
        GBAR(); LGKM0();
        MFMA16(1);
        GBAR();

        // phase 3: (mh0, k1)
        DSREAD_A(1, 0); DSREAD_B(1);
        if (t + 2 < NT) STG_A(t + 2, 0);
        GBAR(); LGKM0();
        MFMA16(0);
        GBAR();

        // phase 4: (mh1, k1) + counted vmcnt (never 0 in steady state)
        DSREAD_A(1, 1);
        if (t + 2 < NT) {
            STG_B(t + 2, 1);
            asm volatile("s_waitcnt vmcnt(6)" ::: "memory");
        } else {
            asm volatile("s_waitcnt vmcnt(0)" ::: "memory");
        }
        GBAR(); LGKM0();
        MFMA16(1);
        GBAR();
    }

    // ---------------- epilogue (MODE 3: out = x1 + acc, fp32) ----------------
    const int mbase = mt * 256 + mr128;
    const int nbase = nt * 256 + nc64;
#pragma unroll
    for (int i8 = 0; i8 < 8; ++i8)
#pragma unroll
        for (int j = 0; j < 4; ++j)
#pragma unroll
            for (int r = 0; r < 4; ++r) {
                const int m = mbase + i8 * 16 + quad * 4 + r;
                const int n = nbase + j * 16 + lane15;
                const size_t idx = (size_t)m * Nlog + n;
                ((float*)outp)[idx] = (float)extra_bf[idx] + acc[i8][j][r];
            }
}

#undef STG_A
#undef STG_B
#undef DSREAD_A
#undef DSREAD_B
#undef MFMA16
#undef GBAR
#undef LGKM0

// ---------------------------------------------------------------------------
extern "C" void kernel_launch(void* const* d_in, const int* in_sizes, int n_in,
                              void* d_out, int out_size, void* d_ws, size_t ws_size,
                              hipStream_t stream) {
    const float* x        = (const float*)d_in[0];
    const float* rms_w1   = (const float*)d_in[1];
    const float* rms_w2   = (const float*)d_in[2];
    const float* delta_w  = (const float*)d_in[3];
    const float* delta_b  = (const float*)d_in[4];
    const float* b_w      = (const float*)d_in[5];
    const float* b_b      = (const float*)d_in[6];
    const float* A_log    = (const float*)d_in[7];
    const float* log_tau  = (const float*)d_in[8];
    const float* plif_thr = (const float*)d_in[9];
    const float* syn_w    = (const float*)d_in[10];
    const float* syn_b    = (const float*)d_in[11];
    const float* gate_w   = (const float*)d_in[12];
    const float* gate_b   = (const float*)d_in[13];
    const float* ffn_g_w  = (const float*)d_in[14];
    const float* ffn_u_w  = (const float*)d_in[15];
    const float* ffn_d_w  = (const float*)d_in[16];

    char* ws = (char*)d_ws;
    const size_t MB = 1024ull * 1024ull;
    // weights bf16: [0,32MB)
    bf16* wdelta = (bf16*)(ws + 0 * MB);
    bf16* wb     = (bf16*)(ws + 2 * MB);
    bf16* wsyn   = (bf16*)(ws + 4 * MB);
    bf16* wgate  = (bf16*)(ws + 6 * MB);
    bf16* wg     = (bf16*)(ws + 8 * MB);
    bf16* wu     = (bf16*)(ws + 16 * MB);
    bf16* wd     = (bf16*)(ws + 24 * MB);
    // phase-1 buffers (all dead before act is written):
    bf16*     y1      = (bf16*)(ws + 32 * MB);       // 32MB
    uint32_t* ABp     = (uint32_t*)(ws + 64 * MB);   // 64MB
    bf16*     spikein = (bf16*)(ws + 128 * MB);      // 32MB
    // persistent:
    bf16* x1 = (bf16*)(ws + 160 * MB);               // 32MB (bf16)
    bf16* y2 = (bf16*)(ws + 224 * MB);               // 32MB
    // act aliases the dead phase-1 region [32MB,160MB): 16384*4096*2 = 128MB
    bf16* act = (bf16*)(ws + 32 * MB);
    float* outF = (float*)d_out;

    const int DD = D_ * D_;        // 1,048,576
    const int DF = DFF_ * D_;      // 4,194,304
    const int BD = DD / 1024;      // blocks per DxD tensor
    const int BF = DF / 1024;

    // --- fused weight converts (one launch) ---
    CvtArgs ca;
    ca.s[0] = delta_w; ca.d[0] = wdelta;
    ca.s[1] = b_w;     ca.d[1] = wb;
    ca.s[2] = syn_w;   ca.d[2] = wsyn;
    ca.s[3] = gate_w;  ca.d[3] = wgate;
    ca.s[4] = ffn_g_w; ca.d[4] = wg;
    ca.s[5] = ffn_u_w; ca.d[5] = wu;
    ca.s[6] = ffn_d_w; ca.d[6] = wd;
    int acc_blk = 0;
    const int segblk[7] = {BD, BD, BD, BD, BF, BF, BF};
    for (int i = 0; i < 7; ++i) { acc_blk += segblk[i]; ca.nblk[i] = acc_blk; }
    f2bf_all_kernel<<<acc_blk, 256, 0, stream>>>(ca);

    // --- RMSNorm 1 ---
    rmsnorm_kernel<<<M_, 256, 0, stream>>>(x, rms_w1, y1);

    // --- dual GEMM: delta/b -> packed (A_t, b_t) ---
    gemm_kernel<2, 0><<<dim3(D_ / 128, M_ / 128), 256, 0, stream>>>(
        y1, wdelta, wb, M_, D_, D_, delta_b, b_b, A_log, nullptr, ABp);

    // --- chunked fused liquid + PLIF scans ---
    scan_kernel<<<(B_ * SCAN_C * D_) / 256, 256, 0, stream>>>(ABp, log_tau, plif_thr, spikein);

    // --- dual GEMM: syn/gate -> x1 = x + syn*sigmoid(gate) (bf16) ---
    gemm_kernel<2, 1><<<dim3(D_ / 128, M_ / 128), 256, 0, stream>>>(
        spikein, wsyn, wgate, M_, D_, D_, syn_b, gate_b, x, nullptr, x1);

    // --- RMSNorm 2 (bf16 in) ---
    rmsnorm_bf_kernel<<<M_, 256, 0, stream>>>(x1, rms_w2, y2);

    // --- dual GEMM: ffn gate/up -> act = silu(g)*u ---
    gemm_kernel<2, 2><<<dim3(DFF_ / 128, M_ / 128), 256, 0, stream>>>(
        y2, wg, wu, M_, DFF_, D_, nullptr, nullptr, nullptr, nullptr, act);

    // --- GEMM: ffn down + residual -> out (8-phase 256², K=4096, 256 blocks) ---
    gemm8_kernel<3><<<(1024 / 256) * (M_ / 256), 512, 0, stream>>>(
        act, wd, 1024, DFF_, D_, nullptr, nullptr, nullptr, x1, outF);
}

// Round 4
// 883.551 us; speedup vs baseline: 1.1542x; 1.0033x over previous
//
#include <hip/hip_runtime.h>
#include <stdint.h>

#define B_   8
#define T_   2048
#define D_   1024
#define DFF_ 4096
#define M_   (B_ * T_)   // 16384

typedef __bf16 bf16;
typedef bf16  bf16x8 __attribute__((ext_vector_type(8)));
typedef bf16  bf16x4 __attribute__((ext_vector_type(4)));
typedef float f32x4  __attribute__((ext_vector_type(4)));

#define CAST_LDS(p) ((__attribute__((address_space(3))) void*)(p))
#define CAST_GLB(p) ((const __attribute__((address_space(1))) void*)(p))

// ---------------------------------------------------------------------------
// Weight converts.
// cvt_cat16: fp32 -> bf16 with 16-row interleave: dst row d (g=d>>5, rr=d&31):
//   rr<16 -> W1 row g*16+(d&15);  rr>=16 -> W2 row g*16+(d&15).
// This makes each wave's four 16-col j-tiles alternate W1/W2 over the SAME
// logical columns -> dual epilogue is register-local (no LDS exchange).
// ---------------------------------------------------------------------------
struct CatArgs {
    const float* w1[3];
    const float* w2[3];
    bf16* dst[3];
    int end[3];   // cumulative dst-row ends: {2048, 4096, 12288}
};

__global__ __launch_bounds__(256) void cvt_cat16_kernel(CatArgs a) {
    const int b = blockIdx.x;
    const int seg = (b >= a.end[0] ? 1 : 0) + (b >= a.end[1] ? 1 : 0);
    const int d = b - (seg ? a.end[seg - 1] : 0);
    const int rr = d & 31;
    const float* src = ((rr < 16) ? a.w1[seg] : a.w2[seg]) +
                       (size_t)(((d >> 5) << 4) + (d & 15)) * D_;
    bf16* dst = a.dst[seg] + (size_t)d * D_;
    const int t = threadIdx.x;
    const float4 v = ((const float4*)src)[t];
    bf16x4 o;
    o[0] = (bf16)v.x; o[1] = (bf16)v.y; o[2] = (bf16)v.z; o[3] = (bf16)v.w;
    ((bf16x4*)dst)[t] = o;
}

__global__ __launch_bounds__(256) void cvt_plain_kernel(const float* __restrict__ s,
                                                        bf16* __restrict__ d) {
    const int i = (blockIdx.x * 256 + threadIdx.x) * 4;
    const float4 v = *(const float4*)(s + i);
    bf16x4 o;
    o[0] = (bf16)v.x; o[1] = (bf16)v.y; o[2] = (bf16)v.z; o[3] = (bf16)v.w;
    *(bf16x4*)(d + i) = o;
}

// ---------------------------------------------------------------------------
// RMSNorm fp32-in (one block per row, D=1024, 256 threads x float4) -> bf16
// ---------------------------------------------------------------------------
__global__ __launch_bounds__(256) void rmsnorm_kernel(const float* __restrict__ x,
                                                      const float* __restrict__ w,
                                                      bf16* __restrict__ y) {
    const size_t row = blockIdx.x;
    const int t = threadIdx.x;
    const float4 v = ((const float4*)(x + row * D_))[t];
    float ss = v.x * v.x + v.y * v.y + v.z * v.z + v.w * v.w;
#pragma unroll
    for (int off = 32; off; off >>= 1) ss += __shfl_down(ss, off);
    __shared__ float red[4];
    if ((t & 63) == 0) red[t >> 6] = ss;
    __syncthreads();
    const float total = red[0] + red[1] + red[2] + red[3];
    const float rstd = rsqrtf(total * (1.0f / (float)D_) + 1e-6f);
    const float4 wv = ((const float4*)w)[t];
    bf16x4 o;
    o[0] = (bf16)(v.x * rstd * wv.x);
    o[1] = (bf16)(v.y * rstd * wv.y);
    o[2] = (bf16)(v.z * rstd * wv.z);
    o[3] = (bf16)(v.w * rstd * wv.w);
    ((bf16x4*)(y + row * D_))[t] = o;
}

// ---------------------------------------------------------------------------
// RMSNorm bf16-in (x1 path) -> bf16 out
// ---------------------------------------------------------------------------
__global__ __launch_bounds__(256) void rmsnorm_bf_kernel(const bf16* __restrict__ x,
                                                         const float* __restrict__ w,
                                                         bf16* __restrict__ y) {
    const size_t row = blockIdx.x;
    const int t = threadIdx.x;
    const bf16x4 xv = ((const bf16x4*)(x + row * D_))[t];
    float f0 = (float)xv[0], f1 = (float)xv[1], f2 = (float)xv[2], f3 = (float)xv[3];
    float ss = f0 * f0 + f1 * f1 + f2 * f2 + f3 * f3;
#pragma unroll
    for (int off = 32; off; off >>= 1) ss += __shfl_down(ss, off);
    __shared__ float red[4];
    if ((t & 63) == 0) red[t >> 6] = ss;
    __syncthreads();
    const float total = red[0] + red[1] + red[2] + red[3];
    const float rstd = rsqrtf(total * (1.0f / (float)D_) + 1e-6f);
    const float4 wv = ((const float4*)w)[t];
    bf16x4 o;
    o[0] = (bf16)(f0 * rstd * wv.x);
    o[1] = (bf16)(f1 * rstd * wv.y);
    o[2] = (bf16)(f2 * rstd * wv.z);
    o[3] = (bf16)(f3 * rstd * wv.w);
    ((bf16x4*)(y + row * D_))[t] = o;
}

// ---------------------------------------------------------------------------
// Chunked fused liquid-tanh + PLIF scan (warm-up contraction).
// ---------------------------------------------------------------------------
#define SCAN_C  32
#define SCAN_L  (T_ / SCAN_C)   // 64
#define SCAN_W  32
#define SCAN_PF 8

template <int N, int W0>
__device__ __forceinline__ void scan_body(const uint32_t* __restrict__ p,
                                          bf16* __restrict__ o, const int ts,
                                          const float pdec, const float om,
                                          const float th) {
    uint32_t buf[SCAN_PF];
#pragma unroll
    for (int i = 0; i < SCAN_PF; ++i) buf[i] = p[(size_t)i * D_];
    float h = 0.0f, v = 0.0f;
#pragma unroll 8
    for (int k = 0; k < N; ++k) {
        const uint32_t w = buf[k & (SCAN_PF - 1)];
        if (k + SCAN_PF < N) buf[k & (SCAN_PF - 1)] = p[(size_t)(k + SCAN_PF) * D_];
        const float a  = __builtin_bit_cast(float, w << 16);
        const float bb = __builtin_bit_cast(float, w & 0xffff0000u);
        const float xv = fmaf(a, h, bb);
        const float e2 = __expf(2.0f * xv);
        h = 1.0f - __fdividef(2.0f, 1.0f + e2);          // tanh(xv)
        const float vpre = fmaf(pdec, v, om * h);
        const float s = (vpre > th) ? 1.0f : 0.0f;
        v = vpre - s * th;
        if (k >= W0) o[(size_t)(ts + k) * D_] = (bf16)(s + h);
    }
}

__global__ __launch_bounds__(256) void scan_kernel(const uint32_t* __restrict__ ABp,
                                                   const float* __restrict__ log_tau,
                                                   const float* __restrict__ thr,
                                                   bf16* __restrict__ sp) {
    const int g = blockIdx.x * 256 + threadIdx.x;
    const int d = g & (D_ - 1);
    const int bc = g >> 10;
    const int b = bc / SCAN_C;
    const int c = bc % SCAN_C;
    const float pdec = __expf(-__expf(-log_tau[d]));
    const float om = 1.0f - pdec;
    const float th = thr[d];
    const int t0 = c * SCAN_L;
    const uint32_t* base = ABp + (size_t)b * (T_ * D_) + d;
    bf16* o = sp + (size_t)b * (T_ * D_) + d;
    if (c == 0) {
        scan_body<SCAN_L, 0>(base, o, 0, pdec, om, th);
    } else {
        const int ts = t0 - SCAN_W;
        scan_body<SCAN_L + SCAN_W, SCAN_W>(base + (size_t)ts * D_, o, ts, pdec, om, th);
    }
}

// ---------------------------------------------------------------------------
// PERSISTENT 8-phase 256x256 GEMM.  grid = 256 (1 block/CU, no tail).
// Block keeps mt FIXED (A-panel reused across all its tiles) and walks
// nt = nt0 + w*4, w < TPB = NTN/4.  Flat step s = w*NT + t: the 8-phase
// stage schedule (verified rounds 1-3) depends only on relative step
// distance, so the pipeline stays warm across tile boundaries; only the
// B base pointer advances and a register-local epilogue slips between
// phase-4's barrier and the next phase-1.
//   XCD map: mt = (bid&7)*8 + (cu&7), nt0 = cu>>3  (cu = bid>>3) ->
//   concurrent per-XCD set = 8mt x 4nt square (round-3 verified locality).
// cat16 B layout (MODE 0/1/2): j even = W1, j odd = W2 over same logical
// cols -> dual epilogue pairs acc[i8][2jp]/acc[i8][2jp+1] locally.
// MODE 0: delta/b -> pack bf16(A_t)|bf16(b_t)<<16 (u32)
// MODE 1: syn/gate -> out = x + syn*sigmoid(gate) (bf16)
// MODE 2: ffn g/u -> out = silu(g)*u (bf16)
// MODE 3: ffn down (no cat) -> out = x1 + acc (fp32)
// ---------------------------------------------------------------------------

#define STG_A(kt, par, kh)                                                             \
  { bf16* l_ = lA0 + (((par) << 1) + (kh)) * 8192;                                     \
    const bf16* g_ = gA + (kt) * 64 + ((kh) << 5);                                     \
    __builtin_amdgcn_global_load_lds(CAST_GLB(g_), CAST_LDS(l_), 16, 0, 0);            \
    __builtin_amdgcn_global_load_lds(CAST_GLB(g_ + g2), CAST_LDS(l_ + 4096), 16, 0, 0); }
#define STG_B(gb, kt, par, kh)                                                         \
  { bf16* l_ = lB0 + (((par) << 1) + (kh)) * 8192;                                     \
    const bf16* g_ = (gb) + (kt) * 64 + ((kh) << 5);                                   \
    __builtin_amdgcn_global_load_lds(CAST_GLB(g_), CAST_LDS(l_), 16, 0, 0);            \
    __builtin_amdgcn_global_load_lds(CAST_GLB(g_ + g2), CAST_LDS(l_ + 4096), 16, 0, 0); }
#define DSREAD_A(KS, MH)                                                               \
  { const bf16* As_ = smA + (cb + (KS)) * 8192 + swz;                                  \
    _Pragma("unroll")                                                                  \
    for (int i = 0; i < 4; ++i)                                                        \
      af[i] = *(const bf16x8*)(As_ + (mr128 + (MH) * 64 + i * 16 + lane15) * 32);      \
  }
#define DSREAD_B(KS)                                                                   \
  { const bf16* Bs_ = smB + (cb + (KS)) * 8192 + swz;                                  \
    _Pragma("unroll")                                                                  \
    for (int j = 0; j < 4; ++j)                                                        \
      bfr[j] = *(const bf16x8*)(Bs_ + (nc64 + j * 16 + lane15) * 32);                  \
  }
#define MFMA16(MH)                                                                     \
  __builtin_amdgcn_s_setprio(1);                                                       \
  _Pragma("unroll")                                                                    \
  for (int i = 0; i < 4; ++i)                                                          \
    _Pragma("unroll")                                                                  \
    for (int j = 0; j < 4; ++j)                                                        \
      acc[(MH) * 4 + i][j] = __builtin_amdgcn_mfma_f32_16x16x32_bf16(                  \
          af[i], bfr[j], acc[(MH) * 4 + i][j], 0, 0, 0);                               \
  __builtin_amdgcn_s_setprio(0);
#define GBAR() __builtin_amdgcn_s_barrier()
#define LGKM0() asm volatile("s_waitcnt lgkmcnt(0)" ::: "memory")

template <int MODE>
__global__ __launch_bounds__(512, 2) void gemm8p_kernel(
    const bf16* __restrict__ A, const bf16* __restrict__ Bw,
    const int K, const int Nlog, const int NTN,
    const float* __restrict__ b1, const float* __restrict__ b2,
    const float* __restrict__ extra, const bf16* __restrict__ extra_bf,
    void* __restrict__ outp) {
    __shared__ bf16 smem[65536] __attribute__((aligned(16)));   // 128 KiB
    bf16* const smA = smem;             // 4 slots x 8192 elems ([256][32] each)
    bf16* const smB = smem + 32768;

    const int tid = threadIdx.x;
    const int wave = tid >> 6;
    const int lane = tid & 63;
    const int lane15 = lane & 15;
    const int quad = lane >> 4;
    const int mr = wave >> 2;          // 0..1
    const int nc = wave & 3;           // 0..3
    const int mr128 = mr * 128;
    const int nc64 = nc * 64;
    const int swz = (quad ^ ((lane15 >> 1) & 3)) << 3;   // constant per lane

    const int xcd = blockIdx.x & 7;
    const int cu  = blockIdx.x >> 3;    // 0..31
    const int mt  = xcd * 8 + (cu & 7); // fixed per block
    const int nt0 = cu >> 3;            // 0..3
    const int TPB = NTN >> 2;
    const int NT  = K >> 6;
    const int S   = TPB * NT;

    const int srow = tid >> 2;                               // 0..127 (q=0)
    const int scol = (((tid & 3) ^ ((srow >> 1) & 3)) << 3); // pre-swizzled col
    const bf16* const gA = A + (size_t)(mt * 256 + srow) * K + scol;
    const size_t g2 = (size_t)128 * K;                       // q=1: rows +128
    const size_t dB = (size_t)1024 * K;                      // nt += 4 per tile
    const bf16* gBc = Bw + (size_t)(nt0 * 256 + srow) * K + scol;
    bf16* const lA0 = smA + (wave << 9);
    bf16* const lB0 = smB + (wave << 9);

    f32x4 acc[8][4] = {};
    bf16x8 af[4];
    bf16x8 bfr[4];

    // prologue: step 0 fully + 3 half-tiles of step 1 (both in tile 0; NT>=16)
    STG_B(gBc, 0, 0, 0); STG_A(0, 0, 0); STG_B(gBc, 0, 0, 1); STG_A(0, 0, 1);
    asm volatile("s_waitcnt vmcnt(4)" ::: "memory");
    STG_B(gBc, 1, 1, 0); STG_A(1, 1, 0); STG_B(gBc, 1, 1, 1);
    asm volatile("s_waitcnt vmcnt(6)" ::: "memory");
    GBAR();

    for (int w = 0; w < TPB; ++w) {
        const bf16* const gBn = gBc + dB;   // next tile's B base
        for (int t = 0; t < NT; ++t) {
            const int s = w * NT + t;
            const int cb = (t & 1) << 1;                         // = (s&1)<<1
            const int tp1 = (t + 1 == NT) ? 0 : t + 1;           // kt of s+1
            const int tp2 = (t + 2 >= NT) ? t + 2 - NT : t + 2;  // kt of s+2
            const int par1 = (t + 1) & 1;                        // parity of s+1
            const int par2 = t & 1;                              // parity of s+2
            const bf16* const gB2 = (t + 2 >= NT) ? gBn : gBc;
            const bool st1 = (s + 1 < S);
            const bool st2 = (s + 2 < S);

            // phase 1: (mh0, k0)
            DSREAD_A(0, 0); DSREAD_B(0);
            if (st1) STG_A(tp1, par1, 1);
            GBAR(); LGKM0();
            MFMA16(0);
            GBAR();

            // phase 2: (mh1, k0) — B-frags held in regs
            DSREAD_A(0, 1);
            if (st2) STG_B(gB2, tp2, par2, 0);
            GBAR(); LGKM0();
            MFMA16(1);
            GBAR();

            // phase 3: (mh0, k1)
            DSREAD_A(1, 0); DSREAD_B(1);
            if (st2) STG_A(tp2, par2, 0);
            GBAR(); LGKM0();
            MFMA16(0);
            GBAR();

            // phase 4: (mh1, k1) + counted vmcnt (never 0 in steady state)
            DSREAD_A(1, 1);
            if (st2) {
                STG_B(gB2, tp2, par2, 1);
                asm volatile("s_waitcnt vmcnt(6)" ::: "memory");
            } else {
                asm volatile("s_waitcnt vmcnt(0)" ::: "memory");
            }
            GBAR(); LGKM0();
            MFMA16(1);
            GBAR();
        }

        // ---- per-tile epilogue (register-local; LDS untouched, pipeline warm)
        if constexpr (MODE != 3) {
            const int nlog0 = (nt0 + w * 4) * 128 + nc * 32;
            const int mbase = mt * 256 + mr128;
#pragma unroll
            for (int i8 = 0; i8 < 8; ++i8)
#pragma unroll
                for (int jp = 0; jp < 2; ++jp)
#pragma unroll
                    for (int r = 0; r < 4; ++r) {
                        const int m = mbase + i8 * 16 + quad * 4 + r;
                        const int n = nlog0 + jp * 16 + lane15;
                        const size_t idx = (size_t)m * Nlog + n;
                        const float v1 = acc[i8][jp * 2][r];      // W1 side
                        const float v2 = acc[i8][jp * 2 + 1][r];  // W2 side
                        if constexpr (MODE == 0) {
                            const float dl = v1 + b1[n];
                            const float spv = (dl > 20.0f) ? dl : log1pf(__expf(dl));
                            const float bv = spv * (v2 + b2[n]);
                            const float av = __expf(-spv * __expf(extra[n]));
                            const uint32_t pa =
                                (uint32_t)__builtin_bit_cast(unsigned short, (bf16)av);
                            const uint32_t pb =
                                (uint32_t)__builtin_bit_cast(unsigned short, (bf16)bv);
                            ((uint32_t*)outp)[idx] = pa | (pb << 16);
                        } else if constexpr (MODE == 1) {
                            const float syn = v1 + b1[n];
                            const float z = v2 + b2[n];
                            const float gate = 1.0f / (1.0f + __expf(-z));
                            ((bf16*)outp)[idx] = (bf16)(extra[idx] + syn * gate);
                        } else {   // MODE 2
                            const float sg = v1 / (1.0f + __expf(-v1));
                            ((bf16*)outp)[idx] = (bf16)(sg * v2);
                        }
                    }
        } else {   // MODE 3: single-B, direct fp32 write
            const int mbase = mt * 256 + mr128;
            const int nbase = (nt0 + w * 4) * 256 + nc64;
#pragma unroll
            for (int i8 = 0; i8 < 8; ++i8)
#pragma unroll
                for (int j = 0; j < 4; ++j)
#pragma unroll
                    for (int r = 0; r < 4; ++r) {
                        const int m = mbase + i8 * 16 + quad * 4 + r;
                        const int n = nbase + j * 16 + lane15;
                        const size_t idx = (size_t)m * Nlog + n;
                        ((float*)outp)[idx] = (float)extra_bf[idx] + acc[i8][j][r];
                    }
        }

        if (w + 1 < TPB) {
#pragma unroll
            for (int i8 = 0; i8 < 8; ++i8)
#pragma unroll
                for (int j = 0; j < 4; ++j)
                    acc[i8][j] = (f32x4){0.0f, 0.0f, 0.0f, 0.0f};
            gBc = gBn;
        }
    }
}

#undef STG_A
#undef STG_B
#undef DSREAD_A
#undef DSREAD_B
#undef MFMA16
#undef GBAR
#undef LGKM0

// ---------------------------------------------------------------------------
extern "C" void kernel_launch(void* const* d_in, const int* in_sizes, int n_in,
                              void* d_out, int out_size, void* d_ws, size_t ws_size,
                              hipStream_t stream) {
    const float* x        = (const float*)d_in[0];
    const float* rms_w1   = (const float*)d_in[1];
    const float* rms_w2   = (const float*)d_in[2];
    const float* delta_w  = (const float*)d_in[3];
    const float* delta_b  = (const float*)d_in[4];
    const float* b_w      = (const float*)d_in[5];
    const float* b_b      = (const float*)d_in[6];
    const float* A_log    = (const float*)d_in[7];
    const float* log_tau  = (const float*)d_in[8];
    const float* plif_thr = (const float*)d_in[9];
    const float* syn_w    = (const float*)d_in[10];
    const float* syn_b    = (const float*)d_in[11];
    const float* gate_w   = (const float*)d_in[12];
    const float* gate_b   = (const float*)d_in[13];
    const float* ffn_g_w  = (const float*)d_in[14];
    const float* ffn_u_w  = (const float*)d_in[15];
    const float* ffn_d_w  = (const float*)d_in[16];

    char* ws = (char*)d_ws;
    const size_t MB = 1024ull * 1024ull;
    // cat16-interleaved bf16 weights: [0,32MB)
    bf16* wcat_db = (bf16*)(ws + 0 * MB);    // [2048,1024]  4MB
    bf16* wcat_sg = (bf16*)(ws + 4 * MB);    // [2048,1024]  4MB
    bf16* wcat_gu = (bf16*)(ws + 8 * MB);    // [8192,1024] 16MB
    bf16* wd      = (bf16*)(ws + 24 * MB);   // [1024,4096]  8MB
    // phase-1 buffers (all dead before act is written):
    bf16*     y1      = (bf16*)(ws + 32 * MB);       // 32MB
    uint32_t* ABp     = (uint32_t*)(ws + 64 * MB);   // 64MB
    bf16*     spikein = (bf16*)(ws + 128 * MB);      // 32MB
    // persistent:
    bf16* x1 = (bf16*)(ws + 160 * MB);               // 32MB (bf16)
    bf16* y2 = (bf16*)(ws + 224 * MB);               // 32MB
    // act aliases the dead phase-1 region [32MB,160MB): 16384*4096*2 = 128MB
    bf16* act = (bf16*)(ws + 32 * MB);
    float* outF = (float*)d_out;

    // --- weight converts ---
    CatArgs ca;
    ca.w1[0] = delta_w; ca.w2[0] = b_w;     ca.dst[0] = wcat_db;
    ca.w1[1] = syn_w;   ca.w2[1] = gate_w;  ca.dst[1] = wcat_sg;
    ca.w1[2] = ffn_g_w; ca.w2[2] = ffn_u_w; ca.dst[2] = wcat_gu;
    ca.end[0] = 2048; ca.end[1] = 4096; ca.end[2] = 12288;
    cvt_cat16_kernel<<<12288, 256, 0, stream>>>(ca);
    cvt_plain_kernel<<<(D_ * DFF_) / 1024, 256, 0, stream>>>(ffn_d_w, wd);

    // --- RMSNorm 1 ---
    rmsnorm_kernel<<<M_, 256, 0, stream>>>(x, rms_w1, y1);

    // --- dual GEMM (cat16, persistent): delta/b -> packed (A_t, b_t) ---
    gemm8p_kernel<0><<<256, 512, 0, stream>>>(
        y1, wcat_db, D_, D_, 8, delta_b, b_b, A_log, nullptr, ABp);

    // --- chunked fused liquid + PLIF scans ---
    scan_kernel<<<(B_ * SCAN_C * D_) / 256, 256, 0, stream>>>(ABp, log_tau, plif_thr, spikein);

    // --- dual GEMM (cat16, persistent): syn/gate -> x1 = x + syn*sigmoid(gate) ---
    gemm8p_kernel<1><<<256, 512, 0, stream>>>(
        spikein, wcat_sg, D_, D_, 8, syn_b, gate_b, x, nullptr, x1);

    // --- RMSNorm 2 (bf16 in) ---
    rmsnorm_bf_kernel<<<M_, 256, 0, stream>>>(x1, rms_w2, y2);

    // --- dual GEMM (cat16, persistent): ffn gate/up -> act = silu(g)*u ---
    gemm8p_kernel<2><<<256, 512, 0, stream>>>(
        y2, wcat_gu, D_, DFF_, 32, nullptr, nullptr, nullptr, nullptr, act);

    // --- GEMM (persistent, TPB=1): ffn down + residual -> out ---
    gemm8p_kernel<3><<<256, 512, 0, stream>>>(
        act, wd, DFF_, D_, 4, nullptr, nullptr, nullptr, x1, outF);
}

// Round 5
// 880.526 us; speedup vs baseline: 1.1582x; 1.0034x over previous
//
#include <hip/hip_runtime.h>
#include <stdint.h>

#define B_   8
#define T_   2048
#define D_   1024
#define DFF_ 4096
#define M_   (B_ * T_)   // 16384

typedef __bf16 bf16;
typedef bf16  bf16x8 __attribute__((ext_vector_type(8)));
typedef bf16  bf16x4 __attribute__((ext_vector_type(4)));
typedef float f32x4  __attribute__((ext_vector_type(4)));

#define CAST_LDS(p) ((__attribute__((address_space(3))) void*)(p))
#define CAST_GLB(p) ((const __attribute__((address_space(1))) void*)(p))

// ---------------------------------------------------------------------------
// Fused prep kernel: cat16 weight cvt (3 tensors) + plain cvt (ffn_d) +
// RMSNorm1 — all independent, one launch (was 3).
//   blk in [0,12288): cat16 cvt;  [12288,16384): ffn_d cvt;
//   [16384,32768): rmsnorm rows.
// ---------------------------------------------------------------------------
struct PrepArgs {
    const float* w1[3];
    const float* w2[3];
    bf16* dst[3];
    int end[3];            // {2048, 4096, 12288}
    const float* fd;       // ffn_d_w fp32
    bf16* fdd;             // -> wd
    const float* x;
    const float* rw1;
    bf16* y1;
};

__global__ __launch_bounds__(256) void prep_kernel(PrepArgs a) {
    __shared__ float red[4];
    const int blk = blockIdx.x;
    const int t = threadIdx.x;

    if (blk >= 16384) {   // ---- RMSNorm 1 (fp32 in -> bf16) ----
        const size_t row = blk - 16384;
        const float4 v = ((const float4*)(a.x + row * D_))[t];
        float ss = v.x * v.x + v.y * v.y + v.z * v.z + v.w * v.w;
#pragma unroll
        for (int off = 32; off; off >>= 1) ss += __shfl_down(ss, off);
        if ((t & 63) == 0) red[t >> 6] = ss;
        __syncthreads();
        const float total = red[0] + red[1] + red[2] + red[3];
        const float rstd = rsqrtf(total * (1.0f / (float)D_) + 1e-6f);
        const float4 wv = ((const float4*)a.rw1)[t];
        bf16x4 o;
        o[0] = (bf16)(v.x * rstd * wv.x);
        o[1] = (bf16)(v.y * rstd * wv.y);
        o[2] = (bf16)(v.z * rstd * wv.z);
        o[3] = (bf16)(v.w * rstd * wv.w);
        ((bf16x4*)(a.y1 + row * D_))[t] = o;
        return;
    }
    if (blk >= 12288) {   // ---- plain cvt: ffn_d ----
        const int i = ((blk - 12288) * 256 + t) * 4;
        const float4 v = *(const float4*)(a.fd + i);
        bf16x4 o;
        o[0] = (bf16)v.x; o[1] = (bf16)v.y; o[2] = (bf16)v.z; o[3] = (bf16)v.w;
        *(bf16x4*)(a.fdd + i) = o;
        return;
    }
    // ---- cat16 cvt: dst row d (g=d>>5): d&31<16 -> W1 row g*16+(d&15),
    //      else W2 row g*16+(d&15) ----
    const int seg = (blk >= a.end[0] ? 1 : 0) + (blk >= a.end[1] ? 1 : 0);
    const int d = blk - (seg ? a.end[seg - 1] : 0);
    const int rr = d & 31;
    const float* src = ((rr < 16) ? a.w1[seg] : a.w2[seg]) +
                       (size_t)(((d >> 5) << 4) + (d & 15)) * D_;
    bf16* dst = a.dst[seg] + (size_t)d * D_;
    const float4 v = ((const float4*)src)[t];
    bf16x4 o;
    o[0] = (bf16)v.x; o[1] = (bf16)v.y; o[2] = (bf16)v.z; o[3] = (bf16)v.w;
    ((bf16x4*)dst)[t] = o;
}

// ---------------------------------------------------------------------------
// RMSNorm bf16-in (x1 path) -> bf16 out
// ---------------------------------------------------------------------------
__global__ __launch_bounds__(256) void rmsnorm_bf_kernel(const bf16* __restrict__ x,
                                                         const float* __restrict__ w,
                                                         bf16* __restrict__ y) {
    const size_t row = blockIdx.x;
    const int t = threadIdx.x;
    const bf16x4 xv = ((const bf16x4*)(x + row * D_))[t];
    float f0 = (float)xv[0], f1 = (float)xv[1], f2 = (float)xv[2], f3 = (float)xv[3];
    float ss = f0 * f0 + f1 * f1 + f2 * f2 + f3 * f3;
#pragma unroll
    for (int off = 32; off; off >>= 1) ss += __shfl_down(ss, off);
    __shared__ float red[4];
    if ((t & 63) == 0) red[t >> 6] = ss;
    __syncthreads();
    const float total = red[0] + red[1] + red[2] + red[3];
    const float rstd = rsqrtf(total * (1.0f / (float)D_) + 1e-6f);
    const float4 wv = ((const float4*)w)[t];
    bf16x4 o;
    o[0] = (bf16)(f0 * rstd * wv.x);
    o[1] = (bf16)(f1 * rstd * wv.y);
    o[2] = (bf16)(f2 * rstd * wv.z);
    o[3] = (bf16)(f3 * rstd * wv.w);
    ((bf16x4*)(y + row * D_))[t] = o;
}

// ---------------------------------------------------------------------------
// Chunked fused liquid-tanh + PLIF scan (warm-up contraction).
// ---------------------------------------------------------------------------
#define SCAN_C  32
#define SCAN_L  (T_ / SCAN_C)   // 64
#define SCAN_W  32
#define SCAN_PF 8

template <int N, int W0>
__device__ __forceinline__ void scan_body(const uint32_t* __restrict__ p,
                                          bf16* __restrict__ o, const int ts,
                                          const float pdec, const float om,
                                          const float th) {
    uint32_t buf[SCAN_PF];
#pragma unroll
    for (int i = 0; i < SCAN_PF; ++i) buf[i] = p[(size_t)i * D_];
    float h = 0.0f, v = 0.0f;
#pragma unroll 8
    for (int k = 0; k < N; ++k) {
        const uint32_t w = buf[k & (SCAN_PF - 1)];
        if (k + SCAN_PF < N) buf[k & (SCAN_PF - 1)] = p[(size_t)(k + SCAN_PF) * D_];
        const float a  = __builtin_bit_cast(float, w << 16);
        const float bb = __builtin_bit_cast(float, w & 0xffff0000u);
        const float xv = fmaf(a, h, bb);
        const float e2 = __expf(2.0f * xv);
        h = 1.0f - __fdividef(2.0f, 1.0f + e2);          // tanh(xv)
        const float vpre = fmaf(pdec, v, om * h);
        const float s = (vpre > th) ? 1.0f : 0.0f;
        v = vpre - s * th;
        if (k >= W0) o[(size_t)(ts + k) * D_] = (bf16)(s + h);
    }
}

__global__ __launch_bounds__(256) void scan_kernel(const uint32_t* __restrict__ ABp,
                                                   const float* __restrict__ log_tau,
                                                   const float* __restrict__ thr,
                                                   bf16* __restrict__ sp) {
    const int g = blockIdx.x * 256 + threadIdx.x;
    const int d = g & (D_ - 1);
    const int bc = g >> 10;
    const int b = bc / SCAN_C;
    const int c = bc % SCAN_C;
    const float pdec = __expf(-__expf(-log_tau[d]));
    const float om = 1.0f - pdec;
    const float th = thr[d];
    const int t0 = c * SCAN_L;
    const uint32_t* base = ABp + (size_t)b * (T_ * D_) + d;
    bf16* o = sp + (size_t)b * (T_ * D_) + d;
    if (c == 0) {
        scan_body<SCAN_L, 0>(base, o, 0, pdec, om, th);
    } else {
        const int ts = t0 - SCAN_W;
        scan_body<SCAN_L + SCAN_W, SCAN_W>(base + (size_t)ts * D_, o, ts, pdec, om, th);
    }
}

// ---------------------------------------------------------------------------
// PERSISTENT 8-phase 256x256 GEMM with FRAGMENT PING-PONG (round 5).
// Round-4 verified: persistence, cat16 dual epilogue, slot schedule,
// both-sides swizzle (bank conflicts = 0), XCD-locality map.
// NEW: next-phase ds_reads are issued INSIDE the MFMA region (fragment
// sets a0/a1, b0/b1 ping-pong) so the LDS pipe (~580 cy/phase of b128
// reads at 85 B/cy) overlaps the matrix pipe (~620 cy/phase of MFMA)
// instead of serializing with it between the barrier pair.
// Slot-liveness for the moved reads re-verified: every prefetched slot
// was staged >=2 phases earlier (covered by the vmcnt(6) chain) and is
// rewritten >=2 barriers after the moved read.  NT even -> slot parity
// continuous across the w (tile) boundary, so nb = cb^2 is exact.
// MODE 0: delta/b -> pack bf16(A_t)|bf16(b_t)<<16 (u32)
// MODE 1: syn/gate -> out = x + syn*sigmoid(gate) (bf16)
// MODE 2: ffn g/u -> out = silu(g)*u (bf16)
// MODE 3: ffn down (no cat) -> out = x1 + acc (fp32)
// ---------------------------------------------------------------------------

#define STG_A(kt, par, kh)                                                             \
  { bf16* l_ = lA0 + (((par) << 1) + (kh)) * 8192;                                     \
    const bf16* g_ = gA + (kt) * 64 + ((kh) << 5);                                     \
    __builtin_amdgcn_global_load_lds(CAST_GLB(g_), CAST_LDS(l_), 16, 0, 0);            \
    __builtin_amdgcn_global_load_lds(CAST_GLB(g_ + g2), CAST_LDS(l_ + 4096), 16, 0, 0); }
#define STG_B(gb, kt, par, kh)                                                         \
  { bf16* l_ = lB0 + (((par) << 1) + (kh)) * 8192;                                     \
    const bf16* g_ = (gb) + (kt) * 64 + ((kh) << 5);                                   \
    __builtin_amdgcn_global_load_lds(CAST_GLB(g_), CAST_LDS(l_), 16, 0, 0);            \
    __builtin_amdgcn_global_load_lds(CAST_GLB(g_ + g2), CAST_LDS(l_ + 4096), 16, 0, 0); }
#define PREF_A(dst, slot, MH)                                                          \
  { const bf16* As_ = smA + (slot) * 8192 + swz;                                       \
    _Pragma("unroll")                                                                  \
    for (int i = 0; i < 4; ++i)                                                        \
      dst[i] = *(const bf16x8*)(As_ + (mr128 + (MH) * 64 + i * 16 + lane15) * 32);     \
  }
#define PREF_B(dst, slot)                                                              \
  { const bf16* Bs_ = smB + (slot) * 8192 + swz;                                       \
    _Pragma("unroll")                                                                  \
    for (int j = 0; j < 4; ++j)                                                        \
      dst[j] = *(const bf16x8*)(Bs_ + (nc64 + j * 16 + lane15) * 32);                  \
  }
#define MFMA16(A_, B_, MH)                                                             \
  _Pragma("unroll")                                                                    \
  for (int i = 0; i < 4; ++i)                                                          \
    _Pragma("unroll")                                                                  \
    for (int j = 0; j < 4; ++j)                                                        \
      acc[(MH) * 4 + i][j] = __builtin_amdgcn_mfma_f32_16x16x32_bf16(                  \
          A_[i], B_[j], acc[(MH) * 4 + i][j], 0, 0, 0);
#define GBAR() __builtin_amdgcn_s_barrier()
#define LGKM0() asm volatile("s_waitcnt lgkmcnt(0)" ::: "memory")

template <int MODE>
__global__ __launch_bounds__(512, 2) void gemm8p_kernel(
    const bf16* __restrict__ A, const bf16* __restrict__ Bw,
    const int K, const int Nlog, const int NTN,
    const float* __restrict__ b1, const float* __restrict__ b2,
    const float* __restrict__ extra, const bf16* __restrict__ extra_bf,
    void* __restrict__ outp) {
    __shared__ bf16 smem[65536] __attribute__((aligned(16)));   // 128 KiB
    bf16* const smA = smem;             // 4 slots x 8192 elems ([256][32] each)
    bf16* const smB = smem + 32768;

    const int tid = threadIdx.x;
    const int wave = tid >> 6;
    const int lane = tid & 63;
    const int lane15 = lane & 15;
    const int quad = lane >> 4;
    const int mr = wave >> 2;          // 0..1
    const int nc = wave & 3;           // 0..3
    const int mr128 = mr * 128;
    const int nc64 = nc * 64;
    const int swz = (quad ^ ((lane15 >> 1) & 3)) << 3;   // constant per lane

    const int xcd = blockIdx.x & 7;
    const int cu  = blockIdx.x >> 3;    // 0..31
    const int mt  = xcd * 8 + (cu & 7); // fixed per block
    const int nt0 = cu >> 3;            // 0..3
    const int TPB = NTN >> 2;
    const int NT  = K >> 6;
    const int S   = TPB * NT;

    const int srow = tid >> 2;                               // 0..127 (q=0)
    const int scol = (((tid & 3) ^ ((srow >> 1) & 3)) << 3); // pre-swizzled col
    const bf16* const gA = A + (size_t)(mt * 256 + srow) * K + scol;
    const size_t g2 = (size_t)128 * K;                       // q=1: rows +128
    const size_t dB = (size_t)1024 * K;                      // nt += 4 per tile
    const bf16* gBc = Bw + (size_t)(nt0 * 256 + srow) * K + scol;
    bf16* const lA0 = smA + (wave << 9);
    bf16* const lB0 = smB + (wave << 9);

    f32x4 acc[8][4] = {};
    bf16x8 a0[4], a1[4], b0[4], b1_[4];

    // prologue: step 0 fully + 3 half-tiles of step 1 (steady pattern)
    STG_B(gBc, 0, 0, 0); STG_A(0, 0, 0); STG_B(gBc, 0, 0, 1); STG_A(0, 0, 1);
    asm volatile("s_waitcnt vmcnt(4)" ::: "memory");
    STG_B(gBc, 1, 1, 0); STG_A(1, 1, 0); STG_B(gBc, 1, 1, 1);
    asm volatile("s_waitcnt vmcnt(6)" ::: "memory");
    GBAR();
    // initial fragment fill for P1 of step 0 (slot 0)
    PREF_A(a0, 0, 0);
    PREF_B(b0, 0);

    for (int w = 0; w < TPB; ++w) {
        const bf16* const gBn = gBc + dB;   // next tile's B base
        for (int t = 0; t < NT; ++t) {
            const int s = w * NT + t;
            const int cb = (t & 1) << 1;                         // this step's slots
            const int nb = cb ^ 2;                               // next step's slots
            const int tp1 = (t + 1 == NT) ? 0 : t + 1;           // kt of s+1
            const int tp2 = (t + 2 >= NT) ? t + 2 - NT : t + 2;  // kt of s+2
            const int par1 = (t + 1) & 1;                        // parity of s+1
            const int par2 = t & 1;                              // parity of s+2
            const bf16* const gB2 = (t + 2 >= NT) ? gBn : gBc;
            const bool st1 = (s + 1 < S);
            const bool st2 = (s + 2 < S);

            // phase 1: MFMA(k0,MH0) using a0,b0; prefetch a1 <- A[k0,MH1]
            if (st1) STG_A(tp1, par1, 1);
            GBAR(); LGKM0();
            __builtin_amdgcn_s_setprio(1);
            PREF_A(a1, cb + 0, 1);
            MFMA16(a0, b0, 0);
            __builtin_amdgcn_s_setprio(0);
            GBAR();

            // phase 2: MFMA(k0,MH1) using a1,b0; prefetch a0 <- A[k1,MH0], b1 <- B[k1]
            if (st2) STG_B(gB2, tp2, par2, 0);
            GBAR(); LGKM0();
            __builtin_amdgcn_s_setprio(1);
            PREF_A(a0, cb + 1, 0);
            PREF_B(b1_, cb + 1);
            MFMA16(a1, b0, 1);
            __builtin_amdgcn_s_setprio(0);
            GBAR();

            // phase 3: MFMA(k1,MH0) using a0,b1; prefetch a1 <- A[k1,MH1]
            if (st2) STG_A(tp2, par2, 0);
            GBAR(); LGKM0();
            __builtin_amdgcn_s_setprio(1);
            PREF_A(a1, cb + 1, 1);
            MFMA16(a0, b1_, 0);
            __builtin_amdgcn_s_setprio(0);
            GBAR();

            // phase 4: MFMA(k1,MH1) using a1,b1; prefetch a0,b0 <- next step k0
            if (st2) {
                STG_B(gB2, tp2, par2, 1);
                asm volatile("s_waitcnt vmcnt(6)" ::: "memory");
            } else {
                asm volatile("s_waitcnt vmcnt(0)" ::: "memory");
            }
            GBAR(); LGKM0();
            __builtin_amdgcn_s_setprio(1);
            PREF_A(a0, nb + 0, 0);
            PREF_B(b0, nb + 0);
            MFMA16(a1, b1_, 1);
            __builtin_amdgcn_s_setprio(0);
            GBAR();
        }

        // ---- per-tile epilogue (register-local; LDS untouched, pipeline warm)
        if constexpr (MODE != 3) {
            const int nlog0 = (nt0 + w * 4) * 128 + nc * 32;
            const int mbase = mt * 256 + mr128;
#pragma unroll
            for (int i8 = 0; i8 < 8; ++i8)
#pragma unroll
                for (int jp = 0; jp < 2; ++jp)
#pragma unroll
                    for (int r = 0; r < 4; ++r) {
                        const int m = mbase + i8 * 16 + quad * 4 + r;
                        const int n = nlog0 + jp * 16 + lane15;
                        const size_t idx = (size_t)m * Nlog + n;
                        const float v1 = acc[i8][jp * 2][r];      // W1 side
                        const float v2 = acc[i8][jp * 2 + 1][r];  // W2 side
                        if constexpr (MODE == 0) {
                            const float dl = v1 + b1[n];
                            const float spv = (dl > 20.0f) ? dl : log1pf(__expf(dl));
                            const float bv = spv * (v2 + b2[n]);
                            const float av = __expf(-spv * __expf(extra[n]));
                            const uint32_t pa =
                                (uint32_t)__builtin_bit_cast(unsigned short, (bf16)av);
                            const uint32_t pb =
                                (uint32_t)__builtin_bit_cast(unsigned short, (bf16)bv);
                            ((uint32_t*)outp)[idx] = pa | (pb << 16);
                        } else if constexpr (MODE == 1) {
                            const float syn = v1 + b1[n];
                            const float z = v2 + b2[n];
                            const float gate = 1.0f / (1.0f + __expf(-z));
                            ((bf16*)outp)[idx] = (bf16)(extra[idx] + syn * gate);
                        } else {   // MODE 2
                            const float sg = v1 / (1.0f + __expf(-v1));
                            ((bf16*)outp)[idx] = (bf16)(sg * v2);
                        }
                    }
        } else {   // MODE 3: single-B, direct fp32 write
            const int mbase = mt * 256 + mr128;
            const int nbase = (nt0 + w * 4) * 256 + nc64;
#pragma unroll
            for (int i8 = 0; i8 < 8; ++i8)
#pragma unroll
                for (int j = 0; j < 4; ++j)
#pragma unroll
                    for (int r = 0; r < 4; ++r) {
                        const int m = mbase + i8 * 16 + quad * 4 + r;
                        const int n = nbase + j * 16 + lane15;
                        const size_t idx = (size_t)m * Nlog + n;
                        ((float*)outp)[idx] = (float)extra_bf[idx] + acc[i8][j][r];
                    }
        }

        if (w + 1 < TPB) {
#pragma unroll
            for (int i8 = 0; i8 < 8; ++i8)
#pragma unroll
                for (int j = 0; j < 4; ++j)
                    acc[i8][j] = (f32x4){0.0f, 0.0f, 0.0f, 0.0f};
            gBc = gBn;
        }
    }
}

#undef STG_A
#undef STG_B
#undef PREF_A
#undef PREF_B
#undef MFMA16
#undef GBAR
#undef LGKM0

// ---------------------------------------------------------------------------
extern "C" void kernel_launch(void* const* d_in, const int* in_sizes, int n_in,
                              void* d_out, int out_size, void* d_ws, size_t ws_size,
                              hipStream_t stream) {
    const float* x        = (const float*)d_in[0];
    const float* rms_w1   = (const float*)d_in[1];
    const float* rms_w2   = (const float*)d_in[2];
    const float* delta_w  = (const float*)d_in[3];
    const float* delta_b  = (const float*)d_in[4];
    const float* b_w      = (const float*)d_in[5];
    const float* b_b      = (const float*)d_in[6];
    const float* A_log    = (const float*)d_in[7];
    const float* log_tau  = (const float*)d_in[8];
    const float* plif_thr = (const float*)d_in[9];
    const float* syn_w    = (const float*)d_in[10];
    const float* syn_b    = (const float*)d_in[11];
    const float* gate_w   = (const float*)d_in[12];
    const float* gate_b   = (const float*)d_in[13];
    const float* ffn_g_w  = (const float*)d_in[14];
    const float* ffn_u_w  = (const float*)d_in[15];
    const float* ffn_d_w  = (const float*)d_in[16];

    char* ws = (char*)d_ws;
    const size_t MB = 1024ull * 1024ull;
    // cat16-interleaved bf16 weights: [0,32MB)
    bf16* wcat_db = (bf16*)(ws + 0 * MB);    // [2048,1024]  4MB
    bf16* wcat_sg = (bf16*)(ws + 4 * MB);    // [2048,1024]  4MB
    bf16* wcat_gu = (bf16*)(ws + 8 * MB);    // [8192,1024] 16MB
    bf16* wd      = (bf16*)(ws + 24 * MB);   // [1024,4096]  8MB
    // phase-1 buffers (all dead before act is written):
    bf16*     y1      = (bf16*)(ws + 32 * MB);       // 32MB
    uint32_t* ABp     = (uint32_t*)(ws + 64 * MB);   // 64MB
    bf16*     spikein = (bf16*)(ws + 128 * MB);      // 32MB
    // persistent:
    bf16* x1 = (bf16*)(ws + 160 * MB);               // 32MB (bf16)
    bf16* y2 = (bf16*)(ws + 224 * MB);               // 32MB
    // act aliases the dead phase-1 region [32MB,160MB): 16384*4096*2 = 128MB
    bf16* act = (bf16*)(ws + 32 * MB);
    float* outF = (float*)d_out;

    // --- fused prep: weight converts + RMSNorm 1 (one launch) ---
    PrepArgs pa;
    pa.w1[0] = delta_w; pa.w2[0] = b_w;     pa.dst[0] = wcat_db;
    pa.w1[1] = syn_w;   pa.w2[1] = gate_w;  pa.dst[1] = wcat_sg;
    pa.w1[2] = ffn_g_w; pa.w2[2] = ffn_u_w; pa.dst[2] = wcat_gu;
    pa.end[0] = 2048; pa.end[1] = 4096; pa.end[2] = 12288;
    pa.fd = ffn_d_w; pa.fdd = wd;
    pa.x = x; pa.rw1 = rms_w1; pa.y1 = y1;
    prep_kernel<<<32768, 256, 0, stream>>>(pa);

    // --- dual GEMM (cat16, persistent): delta/b -> packed (A_t, b_t) ---
    gemm8p_kernel<0><<<256, 512, 0, stream>>>(
        y1, wcat_db, D_, D_, 8, delta_b, b_b, A_log, nullptr, ABp);

    // --- chunked fused liquid + PLIF scans ---
    scan_kernel<<<(B_ * SCAN_C * D_) / 256, 256, 0, stream>>>(ABp, log_tau, plif_thr, spikein);

    // --- dual GEMM (cat16, persistent): syn/gate -> x1 = x + syn*sigmoid(gate) ---
    gemm8p_kernel<1><<<256, 512, 0, stream>>>(
        spikein, wcat_sg, D_, D_, 8, syn_b, gate_b, x, nullptr, x1);

    // --- RMSNorm 2 (bf16 in) ---
    rmsnorm_bf_kernel<<<M_, 256, 0, stream>>>(x1, rms_w2, y2);

    // --- dual GEMM (cat16, persistent): ffn gate/up -> act = silu(g)*u ---
    gemm8p_kernel<2><<<256, 512, 0, stream>>>(
        y2, wcat_gu, D_, DFF_, 32, nullptr, nullptr, nullptr, nullptr, act);

    // --- GEMM (persistent, TPB=1): ffn down + residual -> out ---
    gemm8p_kernel<3><<<256, 512, 0, stream>>>(
        act, wd, DFF_, D_, 4, nullptr, nullptr, nullptr, x1, outF);
}